// Round 1
// 14663.815 us; speedup vs baseline: 1.0932x; 1.0932x over previous
//
#include <hip/hip_runtime.h>
#include <stdint.h>

#define T_SEQ 512
#define BATCH 128
#define HID 1024
#define LAYERS 4
#define NSTAGES (T_SEQ + LAYERS - 1)   // 515
#define NBLK 256
#define WSTRIDE 1032                    // 1024 + 8 pad (shorts): 2064B row -> 2-way bank alias (free)
#define SMEM_BYTES (2*32*WSTRIDE*2 + 8192 + 128)   // weights 132096 + redbuf 8192 + bias 128 = 140416

typedef __attribute__((ext_vector_type(4))) float f32x4;
typedef __attribute__((ext_vector_type(8))) short s16x8;
typedef __attribute__((ext_vector_type(8))) unsigned short u16x8;
typedef __attribute__((ext_vector_type(4))) unsigned short u16x4;

__device__ __forceinline__ unsigned short f2bf(float f) {
    unsigned int x = __builtin_bit_cast(unsigned int, f);
    return (unsigned short)((x + 0x7fffu + ((x >> 16) & 1u)) >> 16);
}

// Persistent cooperative kernel. One block per CU.
// block wid -> (layer, mhalf, nslice): weights for 32 output cols (both W_ih and W_hh,
// K=1024 each) live in LDS for the whole kernel. Waves 0/1: input GEMM rows 0-31/32-63;
// waves 2/3: recurrent GEMM same rows. Cross-phase reduce via LDS. One grid barrier per stage.
__global__ __launch_bounds__(256, 1) void rnn_kernel(
        const float* __restrict__ x,
        const float* __restrict__ Wih,
        const float* __restrict__ Whh,
        const float* __restrict__ bih,
        const float* __restrict__ bhh,
        float* __restrict__ out,
        unsigned int* __restrict__ sync,   // [256] flags + [1] go word, zeroed by memset
        unsigned short* __restrict__ hbf)  // [L][2 parity][B][H] bf16
{
    extern __shared__ char smem[];
    unsigned short* Wlds = (unsigned short*)smem;              // [2][32][WSTRIDE]
    float* redbuf = (float*)(smem + 2 * 32 * WSTRIDE * 2);     // [2][4][64][4] f32
    float* bias_s = (float*)(smem + 2 * 32 * WSTRIDE * 2 + 8192); // [32]

    const int bid = blockIdx.x;
    // XCD-contiguous remap: HW round-robins consecutive bids across 8 XCDs; this puts all
    // 32 blocks of one (layer, mhalf) activation-sharing set on ONE XCD (local L2 re-reads).
    const int wid = ((bid & 7) << 5) | (bid >> 3);
    const int layer = wid >> 6;
    const int mh = (wid >> 5) & 1;
    const int ns = wid & 31;
    const int n0 = ns * 32;
    const int m0 = mh * 64;

    const int tid = threadIdx.x;
    const int wave = tid >> 6;
    const int lane = tid & 63;
    const int ph = wave >> 1;           // 0 = input GEMM, 1 = recurrent GEMM
    const int mrow = (wave & 1) * 32;   // wave's 32-row slice within the 64-row mhalf
    const int l15 = lane & 15;
    const int kq8 = (lane >> 4) << 3;   // element offset of lane's k-group within 32-wide step

    // ---- one-time: weights fp32 -> bf16 into LDS, bias merge ----
    {
        const int p = tid >> 7;              // 0 = W_ih, 1 = W_hh
        const int col = (tid >> 2) & 31;
        const int kq = (tid & 3) * 256;
        const float* __restrict__ wsrc =
            (p == 0 ? Wih : Whh) + (size_t)layer * HID * HID + (size_t)(n0 + col) * HID + kq;
        unsigned short* dst = Wlds + (p * 32 + col) * WSTRIDE + kq;
        #pragma unroll 4
        for (int i = 0; i < 64; ++i) {
            f32x4 v = *(const f32x4*)(wsrc + i * 4);
            u16x4 o;
            o[0] = f2bf(v[0]); o[1] = f2bf(v[1]); o[2] = f2bf(v[2]); o[3] = f2bf(v[3]);
            *(u16x4*)(dst + i * 4) = o;
        }
        if (tid < 32)
            bias_s[tid] = bih[layer * HID + n0 + tid] + bhh[layer * HID + n0 + tid];
    }
    __syncthreads();

    unsigned int* flags = sync;
    unsigned int* go = sync + 256;

    const int bbase0 = (ph * 32 + l15) * WSTRIDE + kq8;        // B-frag cols 0-15
    const int bbase1 = (ph * 32 + 16 + l15) * WSTRIDE + kq8;   // B-frag cols 16-31

    for (int s = 0; s < NSTAGES; ++s) {
        const int tt = s - layer;
        if (tt >= 0 && tt < T_SEQ) {
            const int par = s & 1, prev = par ^ 1;
            f32x4 acc00 = {0.f,0.f,0.f,0.f}, acc01 = {0.f,0.f,0.f,0.f};
            f32x4 acc10 = {0.f,0.f,0.f,0.f}, acc11 = {0.f,0.f,0.f,0.f};

            if (!(ph == 1 && tt == 0)) {   // h(-1) = 0: recurrent waves skip at t==0
                if (ph == 0 && layer == 0) {
                    // A from x (fp32 -> bf16 on the fly), depth-8 register prefetch
                    const float* __restrict__ a0p =
                        x + ((size_t)tt * BATCH + m0 + mrow + l15) * HID + kq8;
                    const float* __restrict__ a1p = a0p + 16 * HID;
                    f32x4 pf[8][2][2];
                    #pragma unroll
                    for (int p = 0; p < 8; ++p) {
                        pf[p][0][0] = *(const f32x4*)(a0p + p * 32);
                        pf[p][0][1] = *(const f32x4*)(a0p + p * 32 + 4);
                        pf[p][1][0] = *(const f32x4*)(a1p + p * 32);
                        pf[p][1][1] = *(const f32x4*)(a1p + p * 32 + 4);
                    }
                    #pragma unroll
                    for (int ks = 0; ks < 32; ++ks) {
                        const int sl = ks & 7;
                        u16x8 av0, av1;
                        #pragma unroll
                        for (int j = 0; j < 4; ++j) {
                            av0[j]     = f2bf(pf[sl][0][0][j]);
                            av0[4 + j] = f2bf(pf[sl][0][1][j]);
                            av1[j]     = f2bf(pf[sl][1][0][j]);
                            av1[4 + j] = f2bf(pf[sl][1][1][j]);
                        }
                        if (ks + 8 < 32) {
                            pf[sl][0][0] = *(const f32x4*)(a0p + (ks + 8) * 32);
                            pf[sl][0][1] = *(const f32x4*)(a0p + (ks + 8) * 32 + 4);
                            pf[sl][1][0] = *(const f32x4*)(a1p + (ks + 8) * 32);
                            pf[sl][1][1] = *(const f32x4*)(a1p + (ks + 8) * 32 + 4);
                        }
                        s16x8 b0 = *(const s16x8*)(Wlds + bbase0 + ks * 32);
                        s16x8 b1 = *(const s16x8*)(Wlds + bbase1 + ks * 32);
                        acc00 = __builtin_amdgcn_mfma_f32_16x16x32_bf16((s16x8)av0, b0, acc00, 0, 0, 0);
                        acc01 = __builtin_amdgcn_mfma_f32_16x16x32_bf16((s16x8)av0, b1, acc01, 0, 0, 0);
                        acc10 = __builtin_amdgcn_mfma_f32_16x16x32_bf16((s16x8)av1, b0, acc10, 0, 0, 0);
                        acc11 = __builtin_amdgcn_mfma_f32_16x16x32_bf16((s16x8)av1, b1, acc11, 0, 0, 0);
                    }
                } else {
                    // A from bf16 hidden state (L2-resident), depth-8 register prefetch
                    const unsigned short* __restrict__ src = (ph == 0)
                        ? hbf + (size_t)((layer - 1) * 2 + prev) * BATCH * HID
                        : hbf + (size_t)(layer * 2 + prev) * BATCH * HID;
                    const unsigned short* __restrict__ a0p =
                        src + (size_t)(m0 + mrow + l15) * HID + kq8;
                    const unsigned short* __restrict__ a1p = a0p + 16 * HID;
                    u16x8 ab[8][2];
                    #pragma unroll
                    for (int p = 0; p < 8; ++p) {
                        ab[p][0] = *(const u16x8*)(a0p + p * 32);
                        ab[p][1] = *(const u16x8*)(a1p + p * 32);
                    }
                    #pragma unroll
                    for (int ks = 0; ks < 32; ++ks) {
                        const int sl = ks & 7;
                        s16x8 a0 = (s16x8)ab[sl][0];
                        s16x8 a1 = (s16x8)ab[sl][1];
                        if (ks + 8 < 32) {
                            ab[sl][0] = *(const u16x8*)(a0p + (ks + 8) * 32);
                            ab[sl][1] = *(const u16x8*)(a1p + (ks + 8) * 32);
                        }
                        s16x8 b0 = *(const s16x8*)(Wlds + bbase0 + ks * 32);
                        s16x8 b1 = *(const s16x8*)(Wlds + bbase1 + ks * 32);
                        acc00 = __builtin_amdgcn_mfma_f32_16x16x32_bf16(a0, b0, acc00, 0, 0, 0);
                        acc01 = __builtin_amdgcn_mfma_f32_16x16x32_bf16(a0, b1, acc01, 0, 0, 0);
                        acc10 = __builtin_amdgcn_mfma_f32_16x16x32_bf16(a1, b0, acc10, 0, 0, 0);
                        acc11 = __builtin_amdgcn_mfma_f32_16x16x32_bf16(a1, b1, acc11, 0, 0, 0);
                    }
                }
            }

            // ---- cross-phase reduce + epilogue ----
            __syncthreads();
            if (ph == 1) {
                float* rb = redbuf + (wave & 1) * 1024;   // [4 tiles][64 lanes][4]
                *(f32x4*)(rb + (0 * 64 + lane) * 4) = acc00;
                *(f32x4*)(rb + (1 * 64 + lane) * 4) = acc01;
                *(f32x4*)(rb + (2 * 64 + lane) * 4) = acc10;
                *(f32x4*)(rb + (3 * 64 + lane) * 4) = acc11;
            }
            __syncthreads();
            if (ph == 0) {
                const float* rb = redbuf + (wave & 1) * 1024;
                acc00 += *(const f32x4*)(rb + (0 * 64 + lane) * 4);
                acc01 += *(const f32x4*)(rb + (1 * 64 + lane) * 4);
                acc10 += *(const f32x4*)(rb + (2 * 64 + lane) * 4);
                acc11 += *(const f32x4*)(rb + (3 * 64 + lane) * 4);
                const float bv0 = bias_s[l15];
                const float bv1 = bias_s[16 + l15];
                unsigned short* __restrict__ hdst =
                    hbf + (size_t)(layer * 2 + par) * BATCH * HID;
                const int rbase = m0 + mrow + ((lane >> 4) << 2);
                #pragma unroll
                for (int mf = 0; mf < 2; ++mf) {
                    f32x4 aN0 = mf ? acc10 : acc00;
                    f32x4 aN1 = mf ? acc11 : acc01;
                    #pragma unroll
                    for (int r = 0; r < 4; ++r) {
                        const int gm = rbase + mf * 16 + r;
                        float v0 = tanhf(aN0[r] + bv0);
                        float v1 = tanhf(aN1[r] + bv1);
                        hdst[(size_t)gm * HID + n0 + l15]      = f2bf(v0);
                        hdst[(size_t)gm * HID + n0 + 16 + l15] = f2bf(v1);
                        if (layer == LAYERS - 1) {
                            out[((size_t)tt * BATCH + gm) * HID + n0 + l15]      = v0;
                            out[((size_t)tt * BATCH + gm) * HID + n0 + 16 + l15] = v1;
                        }
                    }
                }
            }
        }

        // ---- grid barrier with cross-XCD coherence (release: wbl2; acquire: inv) ----
        __syncthreads();                       // drains this block's stores to L2 (vmcnt 0)
        const unsigned int g = (unsigned int)(s + 1);
        if (tid == 0) {
            __threadfence();                   // agent release: write back dirty L2
            __hip_atomic_store(&flags[bid], g, __ATOMIC_RELAXED, __HIP_MEMORY_SCOPE_AGENT);
        }
        if (bid == 0) {
            if (tid < 64) {                    // wave 0 aggregates all 256 flags
                for (;;) {
                    bool ok = true;
                    #pragma unroll
                    for (int j = 0; j < 4; ++j)
                        ok = ok && (__hip_atomic_load(&flags[tid + j * 64], __ATOMIC_RELAXED,
                                                      __HIP_MEMORY_SCOPE_AGENT) >= g);
                    if (__all((int)ok)) break;
                    __builtin_amdgcn_s_sleep(1);
                }
            }
            __syncthreads();
            if (tid == 0)
                __hip_atomic_store(go, g, __ATOMIC_RELAXED, __HIP_MEMORY_SCOPE_AGENT);
        }
        if (tid == 0) {
            while (__hip_atomic_load(go, __ATOMIC_RELAXED, __HIP_MEMORY_SCOPE_AGENT) < g)
                __builtin_amdgcn_s_sleep(1);
            __threadfence();                   // agent acquire: invalidate stale L1/L2
        }
        __syncthreads();
    }
}

extern "C" void kernel_launch(void* const* d_in, const int* in_sizes, int n_in,
                              void* d_out, int out_size, void* d_ws, size_t ws_size,
                              hipStream_t stream) {
    const float* x   = (const float*)d_in[0];
    const float* Wih = (const float*)d_in[1];
    const float* Whh = (const float*)d_in[2];
    const float* bih = (const float*)d_in[3];
    const float* bhh = (const float*)d_in[4];
    float* out = (float*)d_out;

    // ws layout: [0,4096) barrier state (memset 0 each launch) | hbf 2 MiB
    unsigned int* sync = (unsigned int*)d_ws;
    unsigned short* hbf = (unsigned short*)((char*)d_ws + 4096);

    static bool attr_done = false;
    if (!attr_done) {
        hipFuncSetAttribute((const void*)rnn_kernel,
                            hipFuncAttributeMaxDynamicSharedMemorySize, SMEM_BYTES);
        attr_done = true;
    }

    hipMemsetAsync(d_ws, 0, 4096, stream);

    void* args[] = {(void*)&x, (void*)&Wih, (void*)&Whh, (void*)&bih, (void*)&bhh,
                    (void*)&out, (void*)&sync, (void*)&hbf};
    hipLaunchCooperativeKernel((const void*)rnn_kernel, dim3(NBLK), dim3(256),
                               args, SMEM_BYTES, stream);
}